// Round 4
// baseline (638.440 us; speedup 1.0000x reference)
//
#include <hip/hip_runtime.h>
#include <float.h>

#define N_TOK   32768
#define DIM     64
#define K_CODES 8192
#define HWSZ    1024
#define CHW     65536
#define NELEM   2097152

typedef short  bf16x8 __attribute__((ext_vector_type(8)));
typedef float  f32x16 __attribute__((ext_vector_type(16)));

static __device__ __forceinline__ unsigned short f2bf(float x) {
    unsigned u = __float_as_uint(x);
    unsigned r = u + 0x7FFFu + ((u >> 16) & 1u);
    return (unsigned short)(r >> 16);
}
static __device__ __forceinline__ float bf2f(unsigned short h) {
    return __uint_as_float(((unsigned)h) << 16);
}

// ---------------- prep_e: emb -> frag-ordered bf16 hi/lo blob + ||e||^2 ------
// blob layout (ushorts): tile(128)*8192 + ((s*2+p)*2+h)*512 + n*8
__global__ __launch_bounds__(256) void prep_e(const float* __restrict__ emb,
                                              unsigned short* __restrict__ blob,
                                              float* __restrict__ eng) {
    __shared__ float part[512];
    int tile = blockIdx.x;
    #pragma unroll
    for (int u0 = 0; u0 < 2; ++u0) {
        int u = threadIdx.x + u0 * 256;
        int s = u >> 7, h = (u >> 6) & 1, n = u & 63;
        const float* src = emb + (tile * 64 + n) * 64 + s * 16 + h * 8;
        float4 v0 = *(const float4*)src;
        float4 v1 = *(const float4*)(src + 4);
        float x[8] = {v0.x, v0.y, v0.z, v0.w, v1.x, v1.y, v1.z, v1.w};
        unsigned short hi[8], lo[8];
        float ss = 0.f;
        #pragma unroll
        for (int j = 0; j < 8; ++j) {
            hi[j] = f2bf(x[j]);
            lo[j] = f2bf(x[j] - bf2f(hi[j]));
            ss += x[j] * x[j];
        }
        part[u] = ss;
        unsigned short* dhi = blob + (size_t)tile * 8192 + ((s * 2 + 0) * 2 + h) * 512 + n * 8;
        unsigned short* dlo = blob + (size_t)tile * 8192 + ((s * 2 + 1) * 2 + h) * 512 + n * 8;
        uint4 ph, pl;
        ph.x = (unsigned)hi[0] | ((unsigned)hi[1] << 16);
        ph.y = (unsigned)hi[2] | ((unsigned)hi[3] << 16);
        ph.z = (unsigned)hi[4] | ((unsigned)hi[5] << 16);
        ph.w = (unsigned)hi[6] | ((unsigned)hi[7] << 16);
        pl.x = (unsigned)lo[0] | ((unsigned)lo[1] << 16);
        pl.y = (unsigned)lo[2] | ((unsigned)lo[3] << 16);
        pl.z = (unsigned)lo[4] | ((unsigned)lo[5] << 16);
        pl.w = (unsigned)lo[6] | ((unsigned)lo[7] << 16);
        *(uint4*)dhi = ph;
        *(uint4*)dlo = pl;
    }
    __syncthreads();
    if (threadIdx.x < 64) {
        float s = 0.f;
        #pragma unroll
        for (int j = 0; j < 8; ++j) s += part[threadIdx.x + j * 64];
        eng[tile * 64 + threadIdx.x] = s;
    }
}

// ---------------- argmin: MFMA bf16x3, 128 tok x 64 codes, K-split x4 --------
// LDS union: z staging (36,864 B) reused as B double-buffer (32 KB) + red (2 KB)
__global__ __launch_bounds__(256, 4) void vq_argmin(const float* __restrict__ z,
                                                    const unsigned short* __restrict__ blob,
                                                    const float* __restrict__ eng,
                                                    unsigned long long* __restrict__ packed) {
    __shared__ __align__(16) unsigned short smem[18432];   // 36,864 B
    unsigned short* zh = smem;                // 128*72
    unsigned short* zl = smem + 9216;         // 128*72
    unsigned short* bbuf = smem;              // 2*8192 (after z consumed)
    unsigned long long* red = (unsigned long long*)(smem + 16384); // 2048 B

    const int tid  = threadIdx.x;
    const int lane = tid & 63;
    const int wid  = tid >> 6;
    const int wr   = wid >> 1, wc = wid & 1;
    const int l31  = lane & 31, h = lane >> 5;

    const int tb = blockIdx.x & 255;
    const int ks = blockIdx.x >> 8;            // 0..3
    const int n0 = tb * 128;
    const int zbase = (n0 >> 10) * CHW + (n0 & 1023);
    const int t0 = ks * 32, t1 = t0 + 32;      // 32 of 128 tiles (64 codes each)

    // ---- stage z tile (NCHW -> LDS [t][c] bf16 hi/lo, rows padded to 72) ----
    {
        int f4 = tid & 31;       // hw chunk (4 tokens)
        int c0 = tid >> 5;       // 0..7
        #pragma unroll
        for (int r = 0; r < 8; ++r) {
            int c = c0 * 8 + r;
            float4 v = *(const float4*)(z + zbase + c * HWSZ + f4 * 4);
            float x[4] = {v.x, v.y, v.z, v.w};
            #pragma unroll
            for (int e = 0; e < 4; ++e) {
                int t = f4 * 4 + e;
                unsigned short hi = f2bf(x[e]);
                zh[t * 72 + c] = hi;
                zl[t * 72 + c] = f2bf(x[e] - bf2f(hi));
            }
        }
    }

    // ---- prefetch first B tile into regs (overlaps staging latency) ----
    uint4 pf[4];
    {
        const unsigned short* gsrc = blob + (size_t)t0 * 8192;
        #pragma unroll
        for (int c = 0; c < 4; ++c) {
            int ch = wid * 4 + c;
            pf[c] = *(const uint4*)(gsrc + ch * 512 + lane * 8);
        }
    }

    __syncthreads();   // z visible

    // ---- A-fragments (z) into registers: [mt][s][p] ----
    bf16x8 Af[2][4][2];
    #pragma unroll
    for (int mt = 0; mt < 2; ++mt) {
        int row = wr * 64 + mt * 32 + l31;
        #pragma unroll
        for (int s = 0; s < 4; ++s) {
            Af[mt][s][0] = *(const bf16x8*)(&zh[row * 72 + s * 16 + h * 8]);
            Af[mt][s][1] = *(const bf16x8*)(&zl[row * 72 + s * 16 + h * 8]);
        }
    }
    __syncthreads();   // all waves done reading z; smem reusable as bbuf

    // write first tile to buf0
    #pragma unroll
    for (int c = 0; c < 4; ++c) {
        int ch = wid * 4 + c;
        *(uint4*)(&bbuf[ch * 512 + lane * 8]) = pf[c];
    }
    __syncthreads();   // buf0 visible

    float minv0[16], minv1[16];
    int   mini0[16], mini1[16];
    #pragma unroll
    for (int r = 0; r < 16; ++r) {
        minv0[r] = FLT_MAX; minv1[r] = FLT_MAX;
        mini0[r] = 0;       mini1[r] = 0;
    }

    int cur = 0;
    for (int kt = t0; kt < t1; ++kt) {
        bool hn = (kt + 1 < t1);
        if (hn) {
            const unsigned short* gsrc = blob + (size_t)(kt + 1) * 8192;
            #pragma unroll
            for (int c = 0; c < 4; ++c) {
                int ch = wid * 4 + c;
                pf[c] = *(const uint4*)(gsrc + ch * 512 + lane * 8);
            }
        }
        float en = eng[kt * 64 + wc * 32 + l31];
        int  col = kt * 64 + wc * 32 + l31;

        const unsigned short* bb = bbuf + cur * 8192;
        f32x16 ac0, ac1;
        #pragma unroll
        for (int r = 0; r < 16; ++r) { ac0[r] = 0.f; ac1[r] = 0.f; }

        #pragma unroll
        for (int s = 0; s < 4; ++s) {
            bf16x8 bh = *(const bf16x8*)(&bb[((s * 2 + 0) * 2 + h) * 512 + (wc * 32 + l31) * 8]);
            bf16x8 bl = *(const bf16x8*)(&bb[((s * 2 + 1) * 2 + h) * 512 + (wc * 32 + l31) * 8]);
            ac0 = __builtin_amdgcn_mfma_f32_32x32x16_bf16(Af[0][s][1], bh, ac0, 0, 0, 0);
            ac0 = __builtin_amdgcn_mfma_f32_32x32x16_bf16(Af[0][s][0], bl, ac0, 0, 0, 0);
            ac0 = __builtin_amdgcn_mfma_f32_32x32x16_bf16(Af[0][s][0], bh, ac0, 0, 0, 0);
            ac1 = __builtin_amdgcn_mfma_f32_32x32x16_bf16(Af[1][s][1], bh, ac1, 0, 0, 0);
            ac1 = __builtin_amdgcn_mfma_f32_32x32x16_bf16(Af[1][s][0], bl, ac1, 0, 0, 0);
            ac1 = __builtin_amdgcn_mfma_f32_32x32x16_bf16(Af[1][s][0], bh, ac1, 0, 0, 0);
        }

        #pragma unroll
        for (int r = 0; r < 16; ++r) {
            float d0 = fmaf(-2.f, ac0[r], en);
            if (d0 < minv0[r]) { minv0[r] = d0; mini0[r] = col; }
            float d1 = fmaf(-2.f, ac1[r], en);
            if (d1 < minv1[r]) { minv1[r] = d1; mini1[r] = col; }
        }

        if (hn) {
            #pragma unroll
            for (int c = 0; c < 4; ++c) {
                int ch = wid * 4 + c;
                *(uint4*)(&bbuf[(cur ^ 1) * 8192 + ch * 512 + lane * 8]) = pf[c];
            }
        }
        __syncthreads();
        cur ^= 1;
    }

    // ---- reduction: pack (mono<<32|idx), butterfly over 32 cols ----
    #pragma unroll
    for (int mt = 0; mt < 2; ++mt) {
        unsigned long long pv[16];
        #pragma unroll
        for (int r = 0; r < 16; ++r) {
            float v = mt ? minv1[r] : minv0[r];
            int   i = mt ? mini1[r] : mini0[r];
            unsigned u = __float_as_uint(v);
            u = (u & 0x80000000u) ? ~u : (u | 0x80000000u);
            pv[r] = ((unsigned long long)u << 32) | (unsigned)i;
        }
        #pragma unroll
        for (int m = 1; m <= 16; m <<= 1) {
            #pragma unroll
            for (int r = 0; r < 16; ++r) {
                unsigned long long o = __shfl_xor(pv[r], m, 64);
                if (o < pv[r]) pv[r] = o;
            }
        }
        #pragma unroll
        for (int r = 0; r < 16; ++r) {
            if (l31 == r) {
                int row = wr * 64 + mt * 32 + (r & 3) + 8 * (r >> 2) + 4 * h;
                red[row * 2 + wc] = pv[r];
            }
        }
    }
    __syncthreads();
    if (tid < 128) {
        unsigned long long a = red[tid * 2], b = red[tid * 2 + 1];
        unsigned long long m = (b < a) ? b : a;
        atomicMin(&packed[n0 + tid], m);
    }
}

// ---------------- zq_loss: idx out, histogram, z_q_st, loss, z_t -------------
__global__ __launch_bounds__(256) void zq_loss(const float* __restrict__ z,
                                               const float* __restrict__ emb,
                                               const unsigned long long* __restrict__ packed,
                                               float* __restrict__ zq_out,
                                               float* __restrict__ idx_out,
                                               int* __restrict__ idx_i32,
                                               int* __restrict__ cnt_i,
                                               float* __restrict__ loss_sum,
                                               float* __restrict__ z_t) {
    const int tid = threadIdx.x;
    const int n0  = blockIdx.x * 64;
    const int t   = tid >> 2, q = tid & 3;
    const int n   = n0 + t;
    const int idx = (int)(packed[n] & 0xFFFFFFFFull);
    if (q == 0) {
        idx_out[n] = (float)idx;
        idx_i32[n] = idx;
        atomicAdd(&cnt_i[idx], 1);
    }
    const int b = n >> 10, hw = n & 1023;
    const float* er = emb + idx * 64 + q * 16;
    float4 e0 = *(const float4*)er, e1 = *(const float4*)(er + 4);
    float4 e2 = *(const float4*)(er + 8), e3 = *(const float4*)(er + 12);
    float ev[16] = {e0.x, e0.y, e0.z, e0.w, e1.x, e1.y, e1.z, e1.w,
                    e2.x, e2.y, e2.z, e2.w, e3.x, e3.y, e3.z, e3.w};
    float lsum = 0.f;
    #pragma unroll
    for (int j = 0; j < 16; ++j) {
        int c = q * 16 + j;
        float zv = z[b * CHW + c * HWSZ + hw];
        float dd = ev[j] - zv;
        zq_out[b * CHW + c * HWSZ + hw] = zv + dd;
        if (z_t) z_t[n * 64 + c] = zv;
        lsum += dd * dd;
    }
    #pragma unroll
    for (int m = 32; m >= 1; m >>= 1) lsum += __shfl_xor(lsum, m, 64);
    if ((tid & 63) == 0) atomicAdd(loss_sum, lsum);
}

// ---------------- scan_cs: prefix over cnt, cs = 0.99*csz+0.01*cnt, cs_sum ---
__global__ __launch_bounds__(1024) void scan_cs(const int* __restrict__ cnt_i,
                                                const float* __restrict__ csize,
                                                int* __restrict__ offsets,
                                                int* __restrict__ cursor,
                                                float* __restrict__ cs,
                                                float* __restrict__ sums) {  // [0]=cs_sum
    __shared__ int   sc[1024];
    __shared__ float sf[1024];
    const int tid = threadIdx.x;
    int v[8], part = 0;
    float cv[8], fpart = 0.f;
    #pragma unroll
    for (int j = 0; j < 8; ++j) { v[j] = cnt_i[tid * 8 + j]; part += v[j]; }
    #pragma unroll
    for (int j = 0; j < 8; ++j) {
        cv[j] = 0.99f * csize[tid * 8 + j] + 0.01f * (float)v[j];
        cs[tid * 8 + j] = cv[j];
        fpart += cv[j];
    }
    sc[tid] = part;
    sf[tid] = fpart;
    __syncthreads();
    for (int off = 1; off < 1024; off <<= 1) {
        int add = (tid >= off) ? sc[tid - off] : 0;
        __syncthreads();
        sc[tid] += add;
        __syncthreads();
    }
    int run = sc[tid] - part;
    #pragma unroll
    for (int j = 0; j < 8; ++j) {
        offsets[tid * 8 + j] = run;
        cursor[tid * 8 + j]  = run;
        run += v[j];
    }
    for (int off = 512; off >= 1; off >>= 1) {
        if (tid < off) sf[tid] += sf[tid + off];
        __syncthreads();
    }
    if (tid == 0) sums[0] = sf[0];
}

// ---------------- scatter tokens into code-sorted order ----------------
__global__ __launch_bounds__(256) void scatter_kernel(const int* __restrict__ idx_i32,
                                                      int* __restrict__ cursor,
                                                      int* __restrict__ tok_of) {
    int t = blockIdx.x * 256 + threadIdx.x;
    int k = idx_i32[t];
    int pos = atomicAdd(&cursor[k], 1);
    tok_of[pos] = t;
}

// ---------------- ema_reduce: wave per code, coalesced via z_t ----------------
__global__ __launch_bounds__(256) void ema_reduce(const float* __restrict__ z,
                                                  const float* __restrict__ z_t,
                                                  const float* __restrict__ ema_w,
                                                  const int* __restrict__ offsets,
                                                  const int* __restrict__ cnt_i,
                                                  const int* __restrict__ tok_of,
                                                  float* __restrict__ emao_out) {
    const int wid = threadIdx.x >> 6, lane = threadIdx.x & 63;
    const int k = blockIdx.x * 4 + wid;
    const int o0 = offsets[k], c = cnt_i[k];
    float acc = 0.f;
    if (z_t) {
        for (int i = 0; i < c; ++i) {
            int tok = tok_of[o0 + i];
            acc += z_t[tok * 64 + lane];
        }
    } else {
        for (int i = 0; i < c; ++i) {
            int tok = tok_of[o0 + i];
            acc += z[(tok >> 10) * CHW + lane * HWSZ + (tok & 1023)];
        }
    }
    emao_out[k * 64 + lane] = 0.99f * ema_w[k * 64 + lane] + 0.01f * acc;
}

// ---------------- final: cs_norm, emb_out, loss ----------------
__global__ __launch_bounds__(256) void final_kernel(const float* __restrict__ cs,
                                                    const float* __restrict__ sums, // [0]=cs_sum [1]=loss_sum
                                                    const float* __restrict__ emao_out,
                                                    float* __restrict__ csn_out,
                                                    float* __restrict__ embo_out,
                                                    float* __restrict__ loss_out) {
    int g = blockIdx.x * 256 + threadIdx.x;
    float denom = sums[0] + (float)(K_CODES * 1e-5);
    int k = g >> 6;
    float csn = (cs[k] + 1e-5f) / denom;
    embo_out[g] = emao_out[g] / csn;
    if (g < K_CODES) csn_out[g] = (cs[g] + 1e-5f) / denom;
    if (g == 0) *loss_out = 0.25f * sums[1] * (1.0f / (float)NELEM);
}

extern "C" void kernel_launch(void* const* d_in, const int* in_sizes, int n_in,
                              void* d_out, int out_size, void* d_ws, size_t ws_size,
                              hipStream_t stream) {
    (void)in_sizes; (void)n_in; (void)out_size;
    const float* z     = (const float*)d_in[0];
    const float* emb   = (const float*)d_in[1];
    const float* ema_w = (const float*)d_in[2];
    const float* csize = (const float*)d_in[3];

    float* out      = (float*)d_out;
    float* zq_out   = out;
    float* loss_out = out + 2097152;
    float* idx_out  = out + 2097153;
    float* csn_out  = out + 2129921;
    float* emao_out = out + 2138113;
    float* embo_out = out + 2662401;

    char* wsb = (char*)d_ws;
    unsigned short*     blob    = (unsigned short*)(wsb);              // 2,097,152 B
    float*              eng     = (float*)(wsb + 2097152);             // 32 KB
    float*              cs      = (float*)(wsb + 2129920);             // 32 KB
    unsigned long long* packed  = (unsigned long long*)(wsb + 2162688);// 256 KB
    int*                idx_i32 = (int*)(wsb + 2424832);               // 128 KB
    int*                cnt_i   = (int*)(wsb + 2555904);               // 32 KB
    float*              sums    = (float*)(wsb + 2588672);             // 8 B (cs_sum, loss_sum)
    int*                offsets = (int*)(wsb + 2588688);               // 32 KB
    int*                cursor  = (int*)(wsb + 2621456);               // 32 KB
    int*                tok_of  = (int*)(wsb + 2654224);               // 128 KB
    const size_t zt_off = 2785296;
    float* z_t = (ws_size >= zt_off + (size_t)NELEM * 4) ? (float*)(wsb + zt_off) : nullptr;

    hipMemsetAsync(packed, 0xFF, N_TOK * sizeof(unsigned long long), stream);
    hipMemsetAsync(cnt_i, 0, K_CODES * sizeof(int) + 8, stream);  // cnt + sums

    prep_e<<<128, 256, 0, stream>>>(emb, blob, eng);
    vq_argmin<<<1024, 256, 0, stream>>>(z, blob, eng, packed);
    zq_loss<<<N_TOK / 64, 256, 0, stream>>>(z, emb, packed, zq_out, idx_out,
                                            idx_i32, cnt_i, sums + 1, z_t);
    scan_cs<<<1, 1024, 0, stream>>>(cnt_i, csize, offsets, cursor, cs, sums);
    scatter_kernel<<<N_TOK / 256, 256, 0, stream>>>(idx_i32, cursor, tok_of);
    ema_reduce<<<K_CODES / 4, 256, 0, stream>>>(z, z_t, ema_w, offsets, cnt_i,
                                                tok_of, emao_out);
    final_kernel<<<K_CODES * DIM / 256, 256, 0, stream>>>(cs, sums, emao_out,
                                                          csn_out, embo_out, loss_out);
}

// Round 5
// 293.182 us; speedup vs baseline: 2.1776x; 2.1776x over previous
//
#include <hip/hip_runtime.h>
#include <float.h>

#define N_TOK   32768
#define DIM     64
#define K_CODES 8192
#define HWSZ    1024
#define CHW     65536
#define NELEM   2097152

typedef short  bf16x8 __attribute__((ext_vector_type(8)));
typedef float  f32x16 __attribute__((ext_vector_type(16)));

static __device__ __forceinline__ unsigned short f2bf(float x) {
    unsigned u = __float_as_uint(x);
    unsigned r = u + 0x7FFFu + ((u >> 16) & 1u);
    return (unsigned short)(r >> 16);
}
static __device__ __forceinline__ float bf2f(unsigned short h) {
    return __uint_as_float(((unsigned)h) << 16);
}

// ---------------- prep_e: emb -> frag-ordered bf16 hi/lo blob + ||e||^2 ------
// blob layout (ushorts): tile(128)*8192 + ((s*2+p)*2+h)*512 + n*8
__global__ __launch_bounds__(256) void prep_e(const float* __restrict__ emb,
                                              unsigned short* __restrict__ blob,
                                              float* __restrict__ eng) {
    __shared__ float part[512];
    int tile = blockIdx.x;
    #pragma unroll
    for (int u0 = 0; u0 < 2; ++u0) {
        int u = threadIdx.x + u0 * 256;
        int s = u >> 7, h = (u >> 6) & 1, n = u & 63;
        const float* src = emb + (tile * 64 + n) * 64 + s * 16 + h * 8;
        float4 v0 = *(const float4*)src;
        float4 v1 = *(const float4*)(src + 4);
        float x[8] = {v0.x, v0.y, v0.z, v0.w, v1.x, v1.y, v1.z, v1.w};
        unsigned short hi[8], lo[8];
        float ss = 0.f;
        #pragma unroll
        for (int j = 0; j < 8; ++j) {
            hi[j] = f2bf(x[j]);
            lo[j] = f2bf(x[j] - bf2f(hi[j]));
            ss += x[j] * x[j];
        }
        part[u] = ss;
        unsigned short* dhi = blob + (size_t)tile * 8192 + ((s * 2 + 0) * 2 + h) * 512 + n * 8;
        unsigned short* dlo = blob + (size_t)tile * 8192 + ((s * 2 + 1) * 2 + h) * 512 + n * 8;
        uint4 ph, pl;
        ph.x = (unsigned)hi[0] | ((unsigned)hi[1] << 16);
        ph.y = (unsigned)hi[2] | ((unsigned)hi[3] << 16);
        ph.z = (unsigned)hi[4] | ((unsigned)hi[5] << 16);
        ph.w = (unsigned)hi[6] | ((unsigned)hi[7] << 16);
        pl.x = (unsigned)lo[0] | ((unsigned)lo[1] << 16);
        pl.y = (unsigned)lo[2] | ((unsigned)lo[3] << 16);
        pl.z = (unsigned)lo[4] | ((unsigned)lo[5] << 16);
        pl.w = (unsigned)lo[6] | ((unsigned)lo[7] << 16);
        *(uint4*)dhi = ph;
        *(uint4*)dlo = pl;
    }
    __syncthreads();
    if (threadIdx.x < 64) {
        float s = 0.f;
        #pragma unroll
        for (int j = 0; j < 8; ++j) s += part[threadIdx.x + j * 64];
        eng[tile * 64 + threadIdx.x] = s;
    }
}

// ---------------- argmin: barrier-free K-loop, B direct from L2 --------------
// 128 tok x 64 codes per iter, K-split x2, grid 512 = 2 blocks/CU, no spills.
static __device__ __forceinline__ void loadB(const unsigned short* __restrict__ base,
                                             int h, bf16x8* Bh, bf16x8* Bl) {
    #pragma unroll
    for (int s = 0; s < 4; ++s) {
        Bh[s] = *(const bf16x8*)(base + (4 * s + h) * 512);
        Bl[s] = *(const bf16x8*)(base + (4 * s + 2 + h) * 512);
    }
}

__global__ __launch_bounds__(256, 2) void vq_argmin(const float* __restrict__ z,
                                                    const unsigned short* __restrict__ blob,
                                                    const float* __restrict__ eng,
                                                    unsigned long long* __restrict__ packed) {
    __shared__ __align__(16) unsigned short zh[128 * 72];
    __shared__ __align__(16) unsigned short zl[128 * 72];
    __shared__ unsigned long long red[256];

    const int tid  = threadIdx.x;
    const int lane = tid & 63;
    const int wid  = tid >> 6;
    const int wr   = wid >> 1, wc = wid & 1;
    const int l31  = lane & 31, h = lane >> 5;

    const int tb = blockIdx.x & 255;
    const int ks = blockIdx.x >> 8;            // 0..1
    const int n0 = tb * 128;
    const int zbase = (n0 >> 10) * CHW + (n0 & 1023);
    const int t0 = ks * 64, t1 = t0 + 64;      // 64 of 128 tiles (64 codes each)
    const int wcb = (wc * 32 + l31) * 8;       // ushort offset within chunk row
    const int colb = wc * 32 + l31;

    // ---- stage z tile (NCHW -> LDS [t][c] bf16 hi/lo, rows padded to 72) ----
    {
        int f4 = tid & 31;
        int c0 = tid >> 5;
        #pragma unroll
        for (int r = 0; r < 8; ++r) {
            int c = c0 * 8 + r;
            float4 v = *(const float4*)(z + zbase + c * HWSZ + f4 * 4);
            float x[4] = {v.x, v.y, v.z, v.w};
            #pragma unroll
            for (int e = 0; e < 4; ++e) {
                int t = f4 * 4 + e;
                unsigned short hi = f2bf(x[e]);
                zh[t * 72 + c] = hi;
                zl[t * 72 + c] = f2bf(x[e] - bf2f(hi));
            }
        }
    }

    // ---- prefetch first B tile into regs (overlaps z staging latency) ----
    bf16x8 B0h[4], B0l[4], B1h[4], B1l[4];
    float engv0, engv1;
    loadB(blob + (size_t)t0 * 8192 + wcb, h, B0h, B0l);
    engv0 = eng[t0 * 64 + colb];

    __syncthreads();   // z visible

    // ---- A-fragments (z) into registers ----
    bf16x8 Af[2][4][2];
    #pragma unroll
    for (int mt = 0; mt < 2; ++mt) {
        int row = wr * 64 + mt * 32 + l31;
        #pragma unroll
        for (int s = 0; s < 4; ++s) {
            Af[mt][s][0] = *(const bf16x8*)(&zh[row * 72 + s * 16 + h * 8]);
            Af[mt][s][1] = *(const bf16x8*)(&zl[row * 72 + s * 16 + h * 8]);
        }
    }
    // NO barriers from here until the final reduction.

    float minv0[16], minv1[16];
    int   mini0[16], mini1[16];
    #pragma unroll
    for (int r = 0; r < 16; ++r) {
        minv0[r] = FLT_MAX; minv1[r] = FLT_MAX;
        mini0[r] = 0;       mini1[r] = 0;
    }

    #define COMPUTE(KT, BH, BL, ENGV)                                                  \
    {                                                                                  \
        f32x16 ac0, ac1;                                                               \
        _Pragma("unroll")                                                              \
        for (int r = 0; r < 16; ++r) { ac0[r] = 0.f; ac1[r] = 0.f; }                   \
        _Pragma("unroll")                                                              \
        for (int s = 0; s < 4; ++s) {                                                  \
            ac0 = __builtin_amdgcn_mfma_f32_32x32x16_bf16(Af[0][s][1], BH[s], ac0, 0, 0, 0); \
            ac0 = __builtin_amdgcn_mfma_f32_32x32x16_bf16(Af[0][s][0], BL[s], ac0, 0, 0, 0); \
            ac0 = __builtin_amdgcn_mfma_f32_32x32x16_bf16(Af[0][s][0], BH[s], ac0, 0, 0, 0); \
            ac1 = __builtin_amdgcn_mfma_f32_32x32x16_bf16(Af[1][s][1], BH[s], ac1, 0, 0, 0); \
            ac1 = __builtin_amdgcn_mfma_f32_32x32x16_bf16(Af[1][s][0], BL[s], ac1, 0, 0, 0); \
            ac1 = __builtin_amdgcn_mfma_f32_32x32x16_bf16(Af[1][s][0], BH[s], ac1, 0, 0, 0); \
        }                                                                              \
        const int col = (KT) * 64 + colb;                                              \
        _Pragma("unroll")                                                              \
        for (int r = 0; r < 16; ++r) {                                                 \
            float d0 = fmaf(-2.f, ac0[r], ENGV);                                       \
            if (d0 < minv0[r]) { minv0[r] = d0; mini0[r] = col; }                      \
            float d1 = fmaf(-2.f, ac1[r], ENGV);                                       \
            if (d1 < minv1[r]) { minv1[r] = d1; mini1[r] = col; }                      \
        }                                                                              \
    }

    for (int kt = t0; kt < t1; kt += 2) {
        loadB(blob + (size_t)(kt + 1) * 8192 + wcb, h, B1h, B1l);
        engv1 = eng[(kt + 1) * 64 + colb];
        COMPUTE(kt, B0h, B0l, engv0);
        if (kt + 2 < t1) {
            loadB(blob + (size_t)(kt + 2) * 8192 + wcb, h, B0h, B0l);
            engv0 = eng[(kt + 2) * 64 + colb];
        }
        COMPUTE(kt + 1, B1h, B1l, engv1);
    }
    #undef COMPUTE

    // ---- reduction: pack (mono<<32|idx), butterfly over 32 cols ----
    #pragma unroll
    for (int mt = 0; mt < 2; ++mt) {
        unsigned long long pv[16];
        #pragma unroll
        for (int r = 0; r < 16; ++r) {
            float v = mt ? minv1[r] : minv0[r];
            int   i = mt ? mini1[r] : mini0[r];
            unsigned u = __float_as_uint(v);
            u = (u & 0x80000000u) ? ~u : (u | 0x80000000u);
            pv[r] = ((unsigned long long)u << 32) | (unsigned)i;
        }
        #pragma unroll
        for (int m = 1; m <= 16; m <<= 1) {
            #pragma unroll
            for (int r = 0; r < 16; ++r) {
                unsigned long long o = __shfl_xor(pv[r], m, 64);
                if (o < pv[r]) pv[r] = o;
            }
        }
        #pragma unroll
        for (int r = 0; r < 16; ++r) {
            if (l31 == r) {
                int row = wr * 64 + mt * 32 + (r & 3) + 8 * (r >> 2) + 4 * h;
                red[row * 2 + wc] = pv[r];
            }
        }
    }
    __syncthreads();
    if (tid < 128) {
        unsigned long long a = red[tid * 2], b = red[tid * 2 + 1];
        unsigned long long m = (b < a) ? b : a;
        atomicMin(&packed[n0 + tid], m);
    }
}

// ---------------- zq_loss: idx out, histogram, z_q_st, loss, z_t -------------
__global__ __launch_bounds__(256) void zq_loss(const float* __restrict__ z,
                                               const float* __restrict__ emb,
                                               const unsigned long long* __restrict__ packed,
                                               float* __restrict__ zq_out,
                                               float* __restrict__ idx_out,
                                               int* __restrict__ idx_i32,
                                               int* __restrict__ cnt_i,
                                               float* __restrict__ loss_sum,
                                               float* __restrict__ z_t) {
    const int tid = threadIdx.x;
    const int n0  = blockIdx.x * 64;
    const int t   = tid >> 2, q = tid & 3;
    const int n   = n0 + t;
    const int idx = (int)(packed[n] & 0xFFFFFFFFull);
    if (q == 0) {
        idx_out[n] = (float)idx;
        idx_i32[n] = idx;
        atomicAdd(&cnt_i[idx], 1);
    }
    const int b = n >> 10, hw = n & 1023;
    const float* er = emb + idx * 64 + q * 16;
    float4 e0 = *(const float4*)er, e1 = *(const float4*)(er + 4);
    float4 e2 = *(const float4*)(er + 8), e3 = *(const float4*)(er + 12);
    float ev[16] = {e0.x, e0.y, e0.z, e0.w, e1.x, e1.y, e1.z, e1.w,
                    e2.x, e2.y, e2.z, e2.w, e3.x, e3.y, e3.z, e3.w};
    float lsum = 0.f;
    #pragma unroll
    for (int j = 0; j < 16; ++j) {
        int c = q * 16 + j;
        float zv = z[b * CHW + c * HWSZ + hw];
        float dd = ev[j] - zv;
        zq_out[b * CHW + c * HWSZ + hw] = zv + dd;
        if (z_t) z_t[n * 64 + c] = zv;
        lsum += dd * dd;
    }
    #pragma unroll
    for (int m = 32; m >= 1; m >>= 1) lsum += __shfl_xor(lsum, m, 64);
    if ((tid & 63) == 0) atomicAdd(loss_sum, lsum);
}

// ------- scan_cs: prefix over cnt, cs_norm out, loss out, cursor init --------
__global__ __launch_bounds__(1024) void scan_cs(const int* __restrict__ cnt_i,
                                                const float* __restrict__ csize,
                                                const float* __restrict__ loss_sum,
                                                int* __restrict__ offsets,
                                                int* __restrict__ cursor,
                                                float* __restrict__ csn_out,
                                                float* __restrict__ loss_out) {
    __shared__ int   sc[1024];
    __shared__ float sf[1024];
    const int tid = threadIdx.x;
    int v[8], part = 0;
    float cv[8], fpart = 0.f;
    #pragma unroll
    for (int j = 0; j < 8; ++j) { v[j] = cnt_i[tid * 8 + j]; part += v[j]; }
    #pragma unroll
    for (int j = 0; j < 8; ++j) {
        cv[j] = 0.99f * csize[tid * 8 + j] + 0.01f * (float)v[j];
        fpart += cv[j];
    }
    sc[tid] = part;
    sf[tid] = fpart;
    __syncthreads();
    for (int off = 1; off < 1024; off <<= 1) {
        int add = (tid >= off) ? sc[tid - off] : 0;
        __syncthreads();
        sc[tid] += add;
        __syncthreads();
    }
    int run = sc[tid] - part;
    #pragma unroll
    for (int j = 0; j < 8; ++j) {
        offsets[tid * 8 + j] = run;
        cursor[tid * 8 + j]  = run;
        run += v[j];
    }
    for (int off = 512; off >= 1; off >>= 1) {
        if (tid < off) sf[tid] += sf[tid + off];
        __syncthreads();
    }
    float denom = sf[0] + (float)(K_CODES * 1e-5);
    #pragma unroll
    for (int j = 0; j < 8; ++j) csn_out[tid * 8 + j] = (cv[j] + 1e-5f) / denom;
    if (tid == 0) *loss_out = 0.25f * (*loss_sum) * (1.0f / (float)NELEM);
}

// ---------------- scatter tokens into code-sorted order ----------------
__global__ __launch_bounds__(256) void scatter_kernel(const int* __restrict__ idx_i32,
                                                      int* __restrict__ cursor,
                                                      int* __restrict__ tok_of) {
    int t = blockIdx.x * 256 + threadIdx.x;
    int k = idx_i32[t];
    int pos = atomicAdd(&cursor[k], 1);
    tok_of[pos] = t;
}

// ------- ema_final: wave per code -> ema_w_out AND emb_out (fused) -----------
__global__ __launch_bounds__(256) void ema_final(const float* __restrict__ z,
                                                 const float* __restrict__ z_t,
                                                 const float* __restrict__ ema_w,
                                                 const int* __restrict__ offsets,
                                                 const int* __restrict__ cnt_i,
                                                 const int* __restrict__ tok_of,
                                                 const float* __restrict__ csn_out,
                                                 float* __restrict__ emao_out,
                                                 float* __restrict__ embo_out) {
    const int wid = threadIdx.x >> 6, lane = threadIdx.x & 63;
    const int k = blockIdx.x * 4 + wid;
    const int o0 = offsets[k], c = cnt_i[k];
    float acc = 0.f;
    if (z_t) {
        for (int i = 0; i < c; ++i) {
            int tok = tok_of[o0 + i];
            acc += z_t[tok * 64 + lane];
        }
    } else {
        for (int i = 0; i < c; ++i) {
            int tok = tok_of[o0 + i];
            acc += z[(tok >> 10) * CHW + lane * HWSZ + (tok & 1023)];
        }
    }
    float eo = 0.99f * ema_w[k * 64 + lane] + 0.01f * acc;
    emao_out[k * 64 + lane] = eo;
    embo_out[k * 64 + lane] = eo / csn_out[k];
}

extern "C" void kernel_launch(void* const* d_in, const int* in_sizes, int n_in,
                              void* d_out, int out_size, void* d_ws, size_t ws_size,
                              hipStream_t stream) {
    (void)in_sizes; (void)n_in; (void)out_size;
    const float* z     = (const float*)d_in[0];
    const float* emb   = (const float*)d_in[1];
    const float* ema_w = (const float*)d_in[2];
    const float* csize = (const float*)d_in[3];

    float* out      = (float*)d_out;
    float* zq_out   = out;
    float* loss_out = out + 2097152;
    float* idx_out  = out + 2097153;
    float* csn_out  = out + 2129921;
    float* emao_out = out + 2138113;
    float* embo_out = out + 2662401;

    char* wsb = (char*)d_ws;
    unsigned short*     blob    = (unsigned short*)(wsb);              // 2,097,152 B
    float*              eng     = (float*)(wsb + 2097152);             // 32 KB
    unsigned long long* packed  = (unsigned long long*)(wsb + 2129920);// 256 KB
    int*                idx_i32 = (int*)(wsb + 2392064);               // 128 KB
    int*                cnt_i   = (int*)(wsb + 2523136);               // 32 KB
    float*              sums    = (float*)(wsb + 2555904);             // 8 B
    int*                offsets = (int*)(wsb + 2555920);               // 32 KB
    int*                cursor  = (int*)(wsb + 2588688);               // 32 KB
    int*                tok_of  = (int*)(wsb + 2621456);               // 128 KB
    const size_t zt_off = 2752528;
    float* z_t = (ws_size >= zt_off + (size_t)NELEM * 4) ? (float*)(wsb + zt_off) : nullptr;

    hipMemsetAsync(packed, 0xFF, N_TOK * sizeof(unsigned long long), stream);
    hipMemsetAsync(cnt_i, 0, K_CODES * sizeof(int) + 16, stream);  // cnt + sums

    prep_e<<<128, 256, 0, stream>>>(emb, blob, eng);
    vq_argmin<<<512, 256, 0, stream>>>(z, blob, eng, packed);
    zq_loss<<<N_TOK / 64, 256, 0, stream>>>(z, emb, packed, zq_out, idx_out,
                                            idx_i32, cnt_i, sums + 1, z_t);
    scan_cs<<<1, 1024, 0, stream>>>(cnt_i, csize, sums + 1, offsets, cursor,
                                    csn_out, loss_out);
    scatter_kernel<<<N_TOK / 256, 256, 0, stream>>>(idx_i32, cursor, tok_of);
    ema_final<<<K_CODES / 4, 256, 0, stream>>>(z, z_t, ema_w, offsets, cnt_i,
                                               tok_of, csn_out, emao_out, embo_out);
}

// Round 6
// 235.921 us; speedup vs baseline: 2.7062x; 1.2427x over previous
//
#include <hip/hip_runtime.h>
#include <float.h>

#define N_TOK   32768
#define DIM     64
#define K_CODES 8192
#define HWSZ    1024
#define CHW     65536
#define NELEM   2097152

typedef short  bf16x8 __attribute__((ext_vector_type(8)));
typedef float  f32x16 __attribute__((ext_vector_type(16)));

static __device__ __forceinline__ unsigned short f2bf(float x) {
    unsigned u = __float_as_uint(x);
    unsigned r = u + 0x7FFFu + ((u >> 16) & 1u);
    return (unsigned short)(r >> 16);
}
static __device__ __forceinline__ float bf2f(unsigned short h) {
    return __uint_as_float(((unsigned)h) << 16);
}

// ------- prep_e: emb -> frag-ordered bf16 hi/lo blob + ||e||^2 + ws zeroing --
__global__ __launch_bounds__(256) void prep_e(const float* __restrict__ emb,
                                              unsigned short* __restrict__ blob,
                                              float* __restrict__ eng,
                                              unsigned long long* __restrict__ packed,
                                              int* __restrict__ cnt_i,
                                              float* __restrict__ sums) {
    __shared__ float part[512];
    const int gid = blockIdx.x * 256 + threadIdx.x;   // 0..32767
    packed[gid] = ~0ull;                              // init for atomicMin
    if (gid < K_CODES) cnt_i[gid] = 0;
    if (gid < 2) sums[gid] = 0.f;

    int tile = blockIdx.x;
    #pragma unroll
    for (int u0 = 0; u0 < 2; ++u0) {
        int u = threadIdx.x + u0 * 256;
        int s = u >> 7, h = (u >> 6) & 1, n = u & 63;
        const float* src = emb + (tile * 64 + n) * 64 + s * 16 + h * 8;
        float4 v0 = *(const float4*)src;
        float4 v1 = *(const float4*)(src + 4);
        float x[8] = {v0.x, v0.y, v0.z, v0.w, v1.x, v1.y, v1.z, v1.w};
        unsigned short hi[8], lo[8];
        float ss = 0.f;
        #pragma unroll
        for (int j = 0; j < 8; ++j) {
            hi[j] = f2bf(x[j]);
            lo[j] = f2bf(x[j] - bf2f(hi[j]));
            ss += x[j] * x[j];
        }
        part[u] = ss;
        unsigned short* dhi = blob + (size_t)tile * 8192 + ((s * 2 + 0) * 2 + h) * 512 + n * 8;
        unsigned short* dlo = blob + (size_t)tile * 8192 + ((s * 2 + 1) * 2 + h) * 512 + n * 8;
        uint4 ph, pl;
        ph.x = (unsigned)hi[0] | ((unsigned)hi[1] << 16);
        ph.y = (unsigned)hi[2] | ((unsigned)hi[3] << 16);
        ph.z = (unsigned)hi[4] | ((unsigned)hi[5] << 16);
        ph.w = (unsigned)hi[6] | ((unsigned)hi[7] << 16);
        pl.x = (unsigned)lo[0] | ((unsigned)lo[1] << 16);
        pl.y = (unsigned)lo[2] | ((unsigned)lo[3] << 16);
        pl.z = (unsigned)lo[4] | ((unsigned)lo[5] << 16);
        pl.w = (unsigned)lo[6] | ((unsigned)lo[7] << 16);
        *(uint4*)dhi = ph;
        *(uint4*)dlo = pl;
    }
    __syncthreads();
    if (threadIdx.x < 64) {
        float s = 0.f;
        #pragma unroll
        for (int j = 0; j < 8; ++j) s += part[threadIdx.x + j * 64];
        eng[tile * 64 + threadIdx.x] = s;
    }
}

// ---------------- argmin: barrier-free K-loop, B direct from L2 --------------
static __device__ __forceinline__ void loadB(const unsigned short* __restrict__ base,
                                             int h, bf16x8* Bh, bf16x8* Bl) {
    #pragma unroll
    for (int s = 0; s < 4; ++s) {
        Bh[s] = *(const bf16x8*)(base + (4 * s + h) * 512);
        Bl[s] = *(const bf16x8*)(base + (4 * s + 2 + h) * 512);
    }
}

__global__ __launch_bounds__(256, 2) void vq_argmin(const float* __restrict__ z,
                                                    const unsigned short* __restrict__ blob,
                                                    const float* __restrict__ eng,
                                                    unsigned long long* __restrict__ packed) {
    __shared__ __align__(16) unsigned short zh[128 * 72];
    __shared__ __align__(16) unsigned short zl[128 * 72];
    __shared__ unsigned long long red[256];

    const int tid  = threadIdx.x;
    const int lane = tid & 63;
    const int wid  = tid >> 6;
    const int wr   = wid >> 1, wc = wid & 1;
    const int l31  = lane & 31, h = lane >> 5;

    const int tb = blockIdx.x & 255;
    const int ks = blockIdx.x >> 8;            // 0..1
    const int n0 = tb * 128;
    const int zbase = (n0 >> 10) * CHW + (n0 & 1023);
    const int t0 = ks * 64, t1 = t0 + 64;
    const int wcb = (wc * 32 + l31) * 8;
    const int colb = wc * 32 + l31;

    {
        int f4 = tid & 31;
        int c0 = tid >> 5;
        #pragma unroll
        for (int r = 0; r < 8; ++r) {
            int c = c0 * 8 + r;
            float4 v = *(const float4*)(z + zbase + c * HWSZ + f4 * 4);
            float x[4] = {v.x, v.y, v.z, v.w};
            #pragma unroll
            for (int e = 0; e < 4; ++e) {
                int t = f4 * 4 + e;
                unsigned short hi = f2bf(x[e]);
                zh[t * 72 + c] = hi;
                zl[t * 72 + c] = f2bf(x[e] - bf2f(hi));
            }
        }
    }

    bf16x8 B0h[4], B0l[4], B1h[4], B1l[4];
    float engv0, engv1;
    loadB(blob + (size_t)t0 * 8192 + wcb, h, B0h, B0l);
    engv0 = eng[t0 * 64 + colb];

    __syncthreads();

    bf16x8 Af[2][4][2];
    #pragma unroll
    for (int mt = 0; mt < 2; ++mt) {
        int row = wr * 64 + mt * 32 + l31;
        #pragma unroll
        for (int s = 0; s < 4; ++s) {
            Af[mt][s][0] = *(const bf16x8*)(&zh[row * 72 + s * 16 + h * 8]);
            Af[mt][s][1] = *(const bf16x8*)(&zl[row * 72 + s * 16 + h * 8]);
        }
    }

    float minv0[16], minv1[16];
    int   mini0[16], mini1[16];
    #pragma unroll
    for (int r = 0; r < 16; ++r) {
        minv0[r] = FLT_MAX; minv1[r] = FLT_MAX;
        mini0[r] = 0;       mini1[r] = 0;
    }

    #define COMPUTE(KT, BH, BL, ENGV)                                                  \
    {                                                                                  \
        f32x16 ac0, ac1;                                                               \
        _Pragma("unroll")                                                              \
        for (int r = 0; r < 16; ++r) { ac0[r] = 0.f; ac1[r] = 0.f; }                   \
        _Pragma("unroll")                                                              \
        for (int s = 0; s < 4; ++s) {                                                  \
            ac0 = __builtin_amdgcn_mfma_f32_32x32x16_bf16(Af[0][s][1], BH[s], ac0, 0, 0, 0); \
            ac1 = __builtin_amdgcn_mfma_f32_32x32x16_bf16(Af[1][s][1], BH[s], ac1, 0, 0, 0); \
            ac0 = __builtin_amdgcn_mfma_f32_32x32x16_bf16(Af[0][s][0], BL[s], ac0, 0, 0, 0); \
            ac1 = __builtin_amdgcn_mfma_f32_32x32x16_bf16(Af[1][s][0], BL[s], ac1, 0, 0, 0); \
            ac0 = __builtin_amdgcn_mfma_f32_32x32x16_bf16(Af[0][s][0], BH[s], ac0, 0, 0, 0); \
            ac1 = __builtin_amdgcn_mfma_f32_32x32x16_bf16(Af[1][s][0], BH[s], ac1, 0, 0, 0); \
        }                                                                              \
        const int col = (KT) * 64 + colb;                                              \
        _Pragma("unroll")                                                              \
        for (int r = 0; r < 16; ++r) {                                                 \
            float d0 = fmaf(-2.f, ac0[r], ENGV);                                       \
            if (d0 < minv0[r]) { minv0[r] = d0; mini0[r] = col; }                      \
            float d1 = fmaf(-2.f, ac1[r], ENGV);                                       \
            if (d1 < minv1[r]) { minv1[r] = d1; mini1[r] = col; }                      \
        }                                                                              \
    }

    for (int kt = t0; kt < t1; kt += 2) {
        loadB(blob + (size_t)(kt + 1) * 8192 + wcb, h, B1h, B1l);
        engv1 = eng[(kt + 1) * 64 + colb];
        COMPUTE(kt, B0h, B0l, engv0);
        if (kt + 2 < t1) {
            loadB(blob + (size_t)(kt + 2) * 8192 + wcb, h, B0h, B0l);
            engv0 = eng[(kt + 2) * 64 + colb];
        }
        COMPUTE(kt + 1, B1h, B1l, engv1);
    }
    #undef COMPUTE

    #pragma unroll
    for (int mt = 0; mt < 2; ++mt) {
        unsigned long long pv[16];
        #pragma unroll
        for (int r = 0; r < 16; ++r) {
            float v = mt ? minv1[r] : minv0[r];
            int   i = mt ? mini1[r] : mini0[r];
            unsigned u = __float_as_uint(v);
            u = (u & 0x80000000u) ? ~u : (u | 0x80000000u);
            pv[r] = ((unsigned long long)u << 32) | (unsigned)i;
        }
        #pragma unroll
        for (int m = 1; m <= 16; m <<= 1) {
            #pragma unroll
            for (int r = 0; r < 16; ++r) {
                unsigned long long o = __shfl_xor(pv[r], m, 64);
                if (o < pv[r]) pv[r] = o;
            }
        }
        #pragma unroll
        for (int r = 0; r < 16; ++r) {
            if (l31 == r) {
                int row = wr * 64 + mt * 32 + (r & 3) + 8 * (r >> 2) + 4 * h;
                red[row * 2 + wc] = pv[r];
            }
        }
    }
    __syncthreads();
    if (tid < 128) {
        unsigned long long a = red[tid * 2], b = red[tid * 2 + 1];
        unsigned long long m = (b < a) ? b : a;
        atomicMin(&packed[n0 + tid], m);
    }
}

// ------- zq_loss: idx, histogram, z_q_st, loss, z_t, emao init ---------------
__global__ __launch_bounds__(256) void zq_loss(const float* __restrict__ z,
                                               const float* __restrict__ emb,
                                               const float* __restrict__ ema_w,
                                               const unsigned long long* __restrict__ packed,
                                               float* __restrict__ zq_out,
                                               float* __restrict__ idx_out,
                                               int* __restrict__ idx_i32,
                                               int* __restrict__ cnt_i,
                                               float* __restrict__ loss_sum,
                                               float* __restrict__ z_t,
                                               float* __restrict__ emao_out) {
    const int tid = threadIdx.x;
    const int n0  = blockIdx.x * 64;
    const int t   = tid >> 2, q = tid & 3;
    const int n   = n0 + t;
    const int idx = (int)(packed[n] & 0xFFFFFFFFull);
    if (q == 0) {
        idx_out[n] = (float)idx;
        idx_i32[n] = idx;
        atomicAdd(&cnt_i[idx], 1);
    }
    // emao init: 4 strided elements per thread, coalesced scalar stores
    {
        int g = blockIdx.x * 256 + tid;         // 0..131071
        #pragma unroll
        for (int j = 0; j < 4; ++j) {
            int i = g + j * 131072;
            emao_out[i] = 0.99f * ema_w[i];
        }
    }
    const int b = n >> 10, hw = n & 1023;
    const float* er = emb + idx * 64 + q * 16;
    float4 e0 = *(const float4*)er, e1 = *(const float4*)(er + 4);
    float4 e2 = *(const float4*)(er + 8), e3 = *(const float4*)(er + 12);
    float ev[16] = {e0.x, e0.y, e0.z, e0.w, e1.x, e1.y, e1.z, e1.w,
                    e2.x, e2.y, e2.z, e2.w, e3.x, e3.y, e3.z, e3.w};
    float lsum = 0.f;
    #pragma unroll
    for (int j = 0; j < 16; ++j) {
        int c = q * 16 + j;
        float zv = z[b * CHW + c * HWSZ + hw];
        float dd = ev[j] - zv;
        zq_out[b * CHW + c * HWSZ + hw] = zv + dd;
        if (z_t) z_t[n * 64 + c] = zv;
        lsum += dd * dd;
    }
    #pragma unroll
    for (int m = 32; m >= 1; m >>= 1) lsum += __shfl_xor(lsum, m, 64);
    if ((tid & 63) == 0) atomicAdd(loss_sum, lsum);
}

// ------- scan_cs: prefix over cnt -> cursor, cs_norm out, loss out -----------
__global__ __launch_bounds__(1024) void scan_cs(const int* __restrict__ cnt_i,
                                                const float* __restrict__ csize,
                                                const float* __restrict__ loss_sum,
                                                int* __restrict__ cursor,
                                                float* __restrict__ csn_out,
                                                float* __restrict__ loss_out) {
    __shared__ int   sc[1024];
    __shared__ float sf[1024];
    const int tid = threadIdx.x;
    int v[8], part = 0;
    float cv[8], fpart = 0.f;
    #pragma unroll
    for (int j = 0; j < 8; ++j) { v[j] = cnt_i[tid * 8 + j]; part += v[j]; }
    #pragma unroll
    for (int j = 0; j < 8; ++j) {
        cv[j] = 0.99f * csize[tid * 8 + j] + 0.01f * (float)v[j];
        fpart += cv[j];
    }
    sc[tid] = part;
    sf[tid] = fpart;
    __syncthreads();
    for (int off = 1; off < 1024; off <<= 1) {
        int add = (tid >= off) ? sc[tid - off] : 0;
        __syncthreads();
        sc[tid] += add;
        __syncthreads();
    }
    int run = sc[tid] - part;
    #pragma unroll
    for (int j = 0; j < 8; ++j) {
        cursor[tid * 8 + j] = run;
        run += v[j];
    }
    for (int off = 512; off >= 1; off >>= 1) {
        if (tid < off) sf[tid] += sf[tid + off];
        __syncthreads();
    }
    float denom = sf[0] + (float)(K_CODES * 1e-5);
    #pragma unroll
    for (int j = 0; j < 8; ++j) csn_out[tid * 8 + j] = (cv[j] + 1e-5f) / denom;
    if (tid == 0) *loss_out = 0.25f * (*loss_sum) * (1.0f / (float)NELEM);
}

// ------- scatter: tokens into code-sorted order, with code tags --------------
__global__ __launch_bounds__(256) void scatter_kernel(const int* __restrict__ idx_i32,
                                                      int* __restrict__ cursor,
                                                      int* __restrict__ tok_of,
                                                      int* __restrict__ code_of) {
    int t = blockIdx.x * 256 + threadIdx.x;
    int k = idx_i32[t];
    int pos = atomicAdd(&cursor[k], 1);
    tok_of[pos] = t;
    code_of[pos] = k;
}

// ------- ema_acc: balanced 64-position chunks, pipelined loads ---------------
__global__ __launch_bounds__(256) void ema_acc(const float* __restrict__ z,
                                               const float* __restrict__ z_t,
                                               const int* __restrict__ tok_of,
                                               const int* __restrict__ code_of,
                                               float* __restrict__ emao_out) {
    const int wv   = (blockIdx.x * 256 + threadIdx.x) >> 6;   // 0..511
    const int lane = threadIdx.x & 63;
    const int pos0 = wv * 64;
    const int tok  = tok_of[pos0 + lane];
    const int cod  = code_of[pos0 + lane];
    float acc = 0.f;
    #pragma unroll
    for (int g = 0; g < 8; ++g) {
        int tk[8], kk[8];
        #pragma unroll
        for (int j = 0; j < 8; ++j) {
            tk[j] = __shfl(tok, g * 8 + j, 64);
            kk[j] = __shfl(cod, g * 8 + j, 64);
        }
        float v[8];
        if (z_t) {
            #pragma unroll
            for (int j = 0; j < 8; ++j) v[j] = z_t[tk[j] * 64 + lane];
        } else {
            #pragma unroll
            for (int j = 0; j < 8; ++j)
                v[j] = z[(tk[j] >> 10) * CHW + lane * HWSZ + (tk[j] & 1023)];
        }
        int knext = (g < 7) ? __shfl(cod, g * 8 + 8, 64) : -1;
        #pragma unroll
        for (int j = 0; j < 8; ++j) {
            acc += v[j];
            int kn = (j < 7) ? kk[j + 1] : knext;
            if (kn != kk[j]) {
                atomicAdd(&emao_out[kk[j] * 64 + lane], 0.01f * acc);
                acc = 0.f;
            }
        }
    }
}

// ------- final_div: emb_out = emao / csn -------------------------------------
__global__ __launch_bounds__(256) void final_div(const float* __restrict__ emao_out,
                                                 const float* __restrict__ csn_out,
                                                 float* __restrict__ embo_out) {
    int g = blockIdx.x * 256 + threadIdx.x;
    embo_out[g] = emao_out[g] / csn_out[g >> 6];
}

extern "C" void kernel_launch(void* const* d_in, const int* in_sizes, int n_in,
                              void* d_out, int out_size, void* d_ws, size_t ws_size,
                              hipStream_t stream) {
    (void)in_sizes; (void)n_in; (void)out_size;
    const float* z     = (const float*)d_in[0];
    const float* emb   = (const float*)d_in[1];
    const float* ema_w = (const float*)d_in[2];
    const float* csize = (const float*)d_in[3];

    float* out      = (float*)d_out;
    float* zq_out   = out;
    float* loss_out = out + 2097152;
    float* idx_out  = out + 2097153;
    float* csn_out  = out + 2129921;
    float* emao_out = out + 2138113;
    float* embo_out = out + 2662401;

    char* wsb = (char*)d_ws;
    unsigned short*     blob    = (unsigned short*)(wsb);              // 2,097,152 B
    float*              eng     = (float*)(wsb + 2097152);             // 32 KB
    unsigned long long* packed  = (unsigned long long*)(wsb + 2129920);// 256 KB
    int*                code_of = (int*)(wsb + 2129920);               // aliases packed (dead after zq_loss)
    int*                idx_i32 = (int*)(wsb + 2392064);               // 128 KB
    int*                cnt_i   = (int*)(wsb + 2523136);               // 32 KB
    float*              sums    = (float*)(wsb + 2555904);             // 8 B
    int*                cursor  = (int*)(wsb + 2555920);               // 32 KB
    int*                tok_of  = (int*)(wsb + 2588688);               // 128 KB
    const size_t zt_off = 2719760;
    float* z_t = (ws_size >= zt_off + (size_t)NELEM * 4) ? (float*)(wsb + zt_off) : nullptr;

    prep_e<<<128, 256, 0, stream>>>(emb, blob, eng, packed, cnt_i, sums);
    vq_argmin<<<512, 256, 0, stream>>>(z, blob, eng, packed);
    zq_loss<<<N_TOK / 64, 256, 0, stream>>>(z, emb, ema_w, packed, zq_out, idx_out,
                                            idx_i32, cnt_i, sums + 1, z_t, emao_out);
    scan_cs<<<1, 1024, 0, stream>>>(cnt_i, csize, sums + 1, cursor, csn_out, loss_out);
    scatter_kernel<<<N_TOK / 256, 256, 0, stream>>>(idx_i32, cursor, tok_of, code_of);
    ema_acc<<<128, 256, 0, stream>>>(z, z_t, tok_of, code_of, emao_out);
    final_div<<<K_CODES * DIM / 256, 256, 0, stream>>>(emao_out, csn_out, embo_out);
}